// Round 17
// baseline (249.270 us; speedup 1.0000x reference)
//
#include <hip/hip_runtime.h>
#include <hip/hip_bf16.h>
#include <stdint.h>

#define DM   1024
#define DI   2048
#define NST  16
#define BSZ  4
#define SLEN 2048
#define MROWS (BSZ*SLEN)   // 8192
#define CHUNK 32
#define NCH  (SLEN/CHUNK)  // 64
#define DECAYF 0.95f
#define MB (size_t)1048576

typedef _Float16 f16;
typedef __attribute__((ext_vector_type(2))) _Float16 f16x2;
typedef __attribute__((ext_vector_type(4))) _Float16 f16x4;
typedef __attribute__((ext_vector_type(8))) _Float16 f16x8;
typedef __attribute__((ext_vector_type(4))) float f32x4;

__device__ __forceinline__ float silu_f(float v) { return v / (1.f + __expf(-v)); }

__device__ __forceinline__ void gload16(const f16* lds, const f16* g) {
  __builtin_amdgcn_global_load_lds((const __attribute__((address_space(1))) void*)g,
                                   (__attribute__((address_space(3))) void*)lds, 16, 0, 0);
}

// ---- fused preprocessing: x->A1, W_in->B1, W_out->W2, W_x[16:32)->WxC f16, B_log->expBT f16 ----
#define NX4  (MROWS * DM / 4)          // 2,097,152
#define NWI4 (2 * DI * DM / 4)         // 1,048,576
#define NWO4 (DM * DI / 4)             // 524,288
#define NWX4 (NST * DI / 4)            // 8,192
#define NE4  (NST * DI / 4)            // 8,192
__global__ __launch_bounds__(256) void cvt_all(
    const float* __restrict__ x, const float* __restrict__ wi, const float* __restrict__ wo,
    const float* __restrict__ Wx, const float* __restrict__ B_log,
    f16* __restrict__ A1, f16* __restrict__ B1, f16* __restrict__ W2,
    f16* __restrict__ WxC, f16* __restrict__ expBT)
{
  int i = blockIdx.x * 256 + threadIdx.x;
  if (i < NX4 + NWI4 + NWO4 + NWX4) {
    const float* src; f16* dst; int j;
    if (i < NX4)                     { src = x;  dst = A1; j = i; }
    else if (i < NX4 + NWI4)         { src = wi; dst = B1; j = i - NX4; }
    else if (i < NX4 + NWI4 + NWO4)  { src = wo; dst = W2; j = i - NX4 - NWI4; }
    else                             { src = Wx + (size_t)NST * DI; dst = WxC; j = i - NX4 - NWI4 - NWO4; }
    float4 v = ((const float4*)src)[j];
    f16x4 o = {(f16)v.x, (f16)v.y, (f16)v.z, (f16)v.w};
    ((f16x4*)dst)[j] = o;
  } else {
    int j = i - NX4 - NWI4 - NWO4 - NWX4;  // [0, NE4)
    int base = j * 4;                      // element index n*DI+d
    int n = base >> 11, d = base & (DI - 1);
    f16x4 o = {(f16)__expf(B_log[(d + 0) * NST + n]), (f16)__expf(B_log[(d + 1) * NST + n]),
               (f16)__expf(B_log[(d + 2) * NST + n]), (f16)__expf(B_log[(d + 3) * NST + n])};
    ((f16x4*)expBT)[j] = o;
  }
}

// ======= GEMM1: 256x256 tile, BK=32, 4-slot LDS rotation, depth-3 counted-vmcnt =======
#define G1K 1024

__device__ __forceinline__ void stage_t(const f16* __restrict__ mat, int matBase,
                                        int kt, f16* ldsDst, int tid) {
  #pragma unroll
  for (int q = 0; q < 2; ++q) {
    int c = q * 512 + tid;
    int row = c >> 2, p = c & 3;
    int su = p ^ ((row >> 1) & 3);   // pre-swizzled source -> swizzled LDS layout
    gload16(ldsDst + c * 8, mat + (size_t)(matBase + row) * G1K + kt * 32 + su * 8);
  }
}

#define WAITV(n) asm volatile("s_waitcnt vmcnt(" #n ")" ::: "memory")

__global__ __launch_bounds__(512, 2) void gemm1_8ph(
    const f16* __restrict__ A, const f16* __restrict__ Bt,
    f16* __restrict__ Xi, f16* __restrict__ Zs)
{
  __shared__ __align__(16) f16 lds[65536];  // 128KB = 4 slots x 32KB (A@S, B@S+8192)
  const int tid  = threadIdx.x;
  const int lane = tid & 63;
  const int w    = tid >> 6;
  const int wr   = w >> 2, wc = w & 3;
  const int lr   = lane & 15;
  const int lq   = lane >> 4;

  const int nwg = gridDim.x * gridDim.y;
  int wgid = blockIdx.y * gridDim.x + blockIdx.x;
  wgid = (wgid & 7) * (nwg >> 3) + (wgid >> 3);
  const int bx = wgid % gridDim.x;
  const int by = wgid / gridDim.x;
  const int mBase = by * 256;
  const int nBase = bx * 256;

  f32x4 acc[8][4];
  #pragma unroll
  for (int mf = 0; mf < 8; ++mf)
    #pragma unroll
    for (int nf = 0; nf < 4; ++nf)
      acc[mf][nf] = (f32x4){0.f, 0.f, 0.f, 0.f};

  auto rdA = [&](int S, int mf) -> f16x8 {
    int ra = wr * 128 + mf * 16 + lr;
    return *(const f16x8*)&lds[S + ra * 32 + (lq ^ ((ra >> 1) & 3)) * 8];
  };
  auto rdB = [&](int S, int nf) -> f16x8 {
    int rb = wc * 64 + nf * 16 + lr;
    return *(const f16x8*)&lds[S + 8192 + rb * 32 + (lq ^ ((rb >> 1) & 3)) * 8];
  };

  f16x8 bfr[4], afr[8];

#define PH(S, ISSUE, TAIL) do {                                                 \
    _Pragma("unroll")                                                           \
    for (int nf = 0; nf < 4; ++nf) bfr[nf] = rdB((S), nf);                      \
    _Pragma("unroll")                                                           \
    for (int mm = 0; mm < 8; ++mm) afr[mm] = rdA((S), mm);                      \
    ISSUE;                                                                      \
    __builtin_amdgcn_s_barrier();                                               \
    asm volatile("s_waitcnt lgkmcnt(0)" ::: "memory");                          \
    __builtin_amdgcn_sched_barrier(0);                                          \
    __builtin_amdgcn_s_setprio(1);                                              \
    _Pragma("unroll")                                                           \
    for (int mm = 0; mm < 8; ++mm)                                              \
      _Pragma("unroll")                                                         \
      for (int nf = 0; nf < 4; ++nf)                                            \
        acc[mm][nf] = __builtin_amdgcn_mfma_f32_16x16x32_f16(                   \
            afr[mm], bfr[nf], acc[mm][nf], 0, 0, 0);                            \
    __builtin_amdgcn_s_setprio(0);                                              \
    __builtin_amdgcn_sched_barrier(0);                                          \
    TAIL;                                                                       \
    __builtin_amdgcn_s_barrier();                                               \
  } while (0)

  stage_t(A,  mBase, 0, &lds[0],             tid);
  stage_t(Bt, nBase, 0, &lds[8192],          tid);
  stage_t(A,  mBase, 1, &lds[16384],         tid);
  stage_t(Bt, nBase, 1, &lds[16384 + 8192],  tid);
  stage_t(A,  mBase, 2, &lds[32768],         tid);
  stage_t(Bt, nBase, 2, &lds[32768 + 8192],  tid);
  WAITV(8);
  __builtin_amdgcn_s_barrier();

  #pragma unroll
  for (int T = 0; T < 32; ++T) {
    const int S = (T & 3) * 16384;
    const int F = ((T + 3) & 3) * 16384;
    PH(S,
       { if (T + 3 < 32) { stage_t(A, mBase, T + 3, &lds[F], tid);
                           stage_t(Bt, nBase, T + 3, &lds[F + 8192], tid); } },
       { if (T < 29) { WAITV(8); } else if (T == 29) { WAITV(4); } else if (T == 30) { WAITV(0); } });
  }
#undef PH

  __syncthreads();
  const int rq = lq * 4;
  #pragma unroll
  for (int mf = 0; mf < 8; ++mf)
    #pragma unroll
    for (int nf = 0; nf < 4; ++nf)
      #pragma unroll
      for (int r = 0; r < 4; ++r)
        lds[(wr * 128 + mf * 16 + rq + r) * 256 + wc * 64 + nf * 16 + lr] = (f16)acc[mf][nf][r];
  __syncthreads();
  #pragma unroll
  for (int it = 0; it < 16; ++it) {
    int cidx = it * 512 + tid;
    int row = cidx >> 5;
    int col8 = (cidx & 31) * 8;
    int grow = mBase + row;
    int gcol = nBase + col8;
    f16x8 v = *(const f16x8*)&lds[row * 256 + col8];
    if (gcol < DI) *(f16x8*)&Xi[(size_t)grow * DI + gcol] = v;
    else           *(f16x8*)&Zs[(size_t)grow * DI + (gcol - DI)] = v;
  }
}

// ======= GEMM2: 256x128 tile, BK=32, 4-slot rotation, depth-3 counted-vmcnt =======
#define G2K 2048
#define SLOT2 12288   // f16 units per slot: A 256x32 (8192) + B 128x32 (4096)

__device__ __forceinline__ void stage2_A(const f16* __restrict__ mat, int mBase,
                                         int kt, f16* ldsDst, int tid) {
  #pragma unroll
  for (int q = 0; q < 2; ++q) {
    int c = q * 512 + tid;
    int row = c >> 2, p = c & 3;
    int su = p ^ ((row >> 1) & 3);
    gload16(ldsDst + c * 8, mat + (size_t)(mBase + row) * G2K + kt * 32 + su * 8);
  }
}
__device__ __forceinline__ void stage2_B(const f16* __restrict__ mat, int nBase,
                                         int kt, f16* ldsDst, int tid) {
  int c = tid;
  int row = c >> 2, p = c & 3;
  int su = p ^ ((row >> 1) & 3);
  gload16(ldsDst + c * 8, mat + (size_t)(nBase + row) * G2K + kt * 32 + su * 8);
}

__global__ __launch_bounds__(512, 2) void gemm2_pipe(
    const f16* __restrict__ A, const f16* __restrict__ Bt, f16* __restrict__ G)
{
  __shared__ __align__(16) f16 lds[49152];  // 96KB = 4 slots x 24KB
  const int tid  = threadIdx.x;
  const int lane = tid & 63;
  const int w    = tid >> 6;
  const int wr   = w >> 2, wc = w & 3;
  const int lr   = lane & 15;
  const int lq   = lane >> 4;

  const int nwg = gridDim.x * gridDim.y;   // 256, %8==0
  int wgid = blockIdx.y * gridDim.x + blockIdx.x;
  wgid = (wgid & 7) * (nwg >> 3) + (wgid >> 3);
  const int bx = wgid % gridDim.x;
  const int by = wgid / gridDim.x;
  const int mBase = by * 256;
  const int nBase = bx * 128;

  f32x4 acc[8][2];
  #pragma unroll
  for (int mf = 0; mf < 8; ++mf)
    #pragma unroll
    for (int nf = 0; nf < 2; ++nf)
      acc[mf][nf] = (f32x4){0.f, 0.f, 0.f, 0.f};

  auto rdA = [&](int S, int mf) -> f16x8 {
    int ra = wr * 128 + mf * 16 + lr;
    return *(const f16x8*)&lds[S + ra * 32 + (lq ^ ((ra >> 1) & 3)) * 8];
  };
  auto rdB = [&](int S, int nf) -> f16x8 {
    int rb = wc * 32 + nf * 16 + lr;
    return *(const f16x8*)&lds[S + 8192 + rb * 32 + (lq ^ ((rb >> 1) & 3)) * 8];
  };

  f16x8 bfr[2], afr[8];

#define PH2(S, ISSUE, TAIL) do {                                                \
    _Pragma("unroll")                                                           \
    for (int nf = 0; nf < 2; ++nf) bfr[nf] = rdB((S), nf);                      \
    _Pragma("unroll")                                                           \
    for (int mm = 0; mm < 8; ++mm) afr[mm] = rdA((S), mm);                      \
    ISSUE;                                                                      \
    __builtin_amdgcn_s_barrier();                                               \
    asm volatile("s_waitcnt lgkmcnt(0)" ::: "memory");                          \
    __builtin_amdgcn_sched_barrier(0);                                          \
    __builtin_amdgcn_s_setprio(1);                                              \
    _Pragma("unroll")                                                           \
    for (int mm = 0; mm < 8; ++mm)                                              \
      _Pragma("unroll")                                                         \
      for (int nf = 0; nf < 2; ++nf)                                            \
        acc[mm][nf] = __builtin_amdgcn_mfma_f32_16x16x32_f16(                   \
            afr[mm], bfr[nf], acc[mm][nf], 0, 0, 0);                            \
    __builtin_amdgcn_s_setprio(0);                                              \
    __builtin_amdgcn_sched_barrier(0);                                          \
    TAIL;                                                                       \
    __builtin_amdgcn_s_barrier();                                               \
  } while (0)

  stage2_A(A,  mBase, 0, &lds[0],                 tid);
  stage2_B(Bt, nBase, 0, &lds[8192],              tid);
  stage2_A(A,  mBase, 1, &lds[SLOT2],             tid);
  stage2_B(Bt, nBase, 1, &lds[SLOT2 + 8192],      tid);
  stage2_A(A,  mBase, 2, &lds[2 * SLOT2],         tid);
  stage2_B(Bt, nBase, 2, &lds[2 * SLOT2 + 8192],  tid);
  WAITV(6);
  __builtin_amdgcn_s_barrier();

  #pragma unroll
  for (int T = 0; T < 64; ++T) {
    const int S = (T & 3) * SLOT2;
    const int F = ((T + 3) & 3) * SLOT2;
    PH2(S,
        { if (T + 3 < 64) { stage2_A(A, mBase, T + 3, &lds[F], tid);
                            stage2_B(Bt, nBase, T + 3, &lds[F + 8192], tid); } },
        { if (T < 61) { WAITV(6); } else if (T == 61) { WAITV(3); } else if (T == 62) { WAITV(0); } });
  }
#undef PH2

  __syncthreads();
  const int rq = lq * 4;
  #pragma unroll
  for (int mf = 0; mf < 8; ++mf)
    #pragma unroll
    for (int nf = 0; nf < 2; ++nf)
      #pragma unroll
      for (int r = 0; r < 4; ++r)
        lds[(wr * 128 + mf * 16 + rq + r) * 128 + wc * 32 + nf * 16 + lr] = (f16)acc[mf][nf][r];
  __syncthreads();
  #pragma unroll
  for (int it = 0; it < 8; ++it) {
    int cidx = it * 512 + tid;
    int row = cidx >> 4;
    int col8 = (cidx & 15) * 8;
    f16x8 v = *(const f16x8*)&lds[row * 128 + col8];
    *(f16x8*)&G[(size_t)(mBase + row) * DM + nBase + col8] = v;
  }
}

// ---------------- depthwise causal conv (w=4) + SiLU + chunked local scan ----------------
// grid: (NCH, BSZ), block 256, 8 d per thread (f16x8 = 16B/lane). CHUNK=32.
__global__ __launch_bounds__(256) void conv_scan(
    const f16* __restrict__ Xi, const float* __restrict__ convW, const float* __restrict__ convB,
    f16* __restrict__ Xc, f16* __restrict__ Hl, float* __restrict__ L)
{
  const int tid = threadIdx.x;
  const int d0 = tid * 8;
  const int ch = blockIdx.x;
  const int b  = blockIdx.y;
  const int t0 = ch * CHUNK;

  float w0[8], w1[8], w2[8], w3[8], cb[8];
  #pragma unroll
  for (int i = 0; i < 8; ++i) {
    float4 wv = ((const float4*)convW)[d0 + i];
    w0[i] = wv.x; w1[i] = wv.y; w2[i] = wv.z; w3[i] = wv.w;
    cb[i] = convB[d0 + i];
  }

  float xm3[8], xm2[8], xm1[8];
  auto loadrow = [&](int t, float* dst) {
    if (t < 0) {
      #pragma unroll
      for (int i = 0; i < 8; ++i) dst[i] = 0.f;
      return;
    }
    f16x8 v = *(const f16x8*)&Xi[((size_t)(b * SLEN + t)) * DI + d0];
    #pragma unroll
    for (int i = 0; i < 8; ++i) dst[i] = (float)v[i];
  };
  loadrow(t0 - 3, xm3); loadrow(t0 - 2, xm2); loadrow(t0 - 1, xm1);

  float h[8] = {0.f, 0.f, 0.f, 0.f, 0.f, 0.f, 0.f, 0.f};
  for (int t = 0; t < CHUNK; ++t) {
    const size_t ro = ((size_t)(b * SLEN + t0 + t)) * DI + d0;
    f16x8 xv = *(const f16x8*)&Xi[ro];
    f16x8 xco, hho;
    #pragma unroll
    for (int i = 0; i < 8; ++i) {
      float xt = (float)xv[i];
      float c = cb[i] + w0[i]*xm3[i] + w1[i]*xm2[i] + w2[i]*xm1[i] + w3[i]*xt;
      float xc = silu_f(c);
      h[i] = DECAYF * h[i] + xc;
      xco[i] = (f16)xc;
      hho[i] = (f16)h[i];
      xm3[i] = xm2[i]; xm2[i] = xm1[i]; xm1[i] = xt;
    }
    *(f16x8*)&Xc[ro] = xco;
    *(f16x8*)&Hl[ro] = hho;
  }
  const size_t lo = ((size_t)(b * NCH + ch)) * DI + d0;
  float4 l0 = {h[0], h[1], h[2], h[3]};
  float4 l1 = {h[4], h[5], h[6], h[7]};
  *(float4*)&L[lo] = l0;
  *(float4*)&L[lo + 4] = l1;
}

// ---- fused mid: sc_gemm (blocks 0..2047, wave-per-row, no LDS) + carry_scan (blocks 2048..2079) ----
__global__ __launch_bounds__(256) void sc_carry(
    const f16* __restrict__ Xc, const f16* __restrict__ WxC, const float* __restrict__ L,
    float* __restrict__ sC, f16* __restrict__ Carry)
{
  const int tid = threadIdx.x;
  if (blockIdx.x >= 2048) {
    // ---- carry part: identical to r8-proven carry_scan ----
    int i = (blockIdx.x - 2048) * 256 + tid;  // 0..8191
    int b = i >> 11, d = i & (DI - 1);
    float dp = 1.f;
    #pragma unroll
    for (int k = 0; k < CHUNK; ++k) dp *= DECAYF;
    float c = 0.f;
    for (int ch0 = 0; ch0 < NCH; ch0 += 8) {
      float lv[8];
      #pragma unroll
      for (int k = 0; k < 8; ++k)
        lv[k] = L[((size_t)(b * NCH + ch0 + k)) * DI + d];
      #pragma unroll
      for (int k = 0; k < 8; ++k) {
        c = dp * c + lv[k];
        Carry[((size_t)(b * NCH + ch0 + k)) * DI + d] = (f16)c;
      }
    }
    return;
  }
  // ---- sc part: identical to r11-proven sc_gemm ----
  const int m = blockIdx.x * 4 + (tid >> 6);
  const int lane = tid & 63;
  float acc[16];
  #pragma unroll
  for (int n = 0; n < 16; ++n) acc[n] = 0.f;
  #pragma unroll
  for (int it = 0; it < DI / 512; ++it) {
    int d = it * 512 + lane * 8;
    f16x8 xv = *(const f16x8*)&Xc[(size_t)m * DI + d];
    #pragma unroll
    for (int n = 0; n < 16; ++n) {
      f16x8 wv = *(const f16x8*)&WxC[(size_t)n * DI + d];
      float s = 0.f;
      #pragma unroll
      for (int i = 0; i < 8; ++i) s += (float)xv[i] * (float)wv[i];
      acc[n] += s;
    }
  }
  #pragma unroll
  for (int n = 0; n < 16; ++n) {
    #pragma unroll
    for (int off = 32; off > 0; off >>= 1) acc[n] += __shfl_xor(acc[n], off);
  }
  if (lane == 0) {
    #pragma unroll
    for (int n = 0; n < 16; ++n) sC[m * 16 + n] = acc[n];
  }
}

// ---------------- Y = (Hl + coef*Carry) * (sC·expBT) * silu(Z) ; f16 out ----------------
__global__ __launch_bounds__(256) void ew_y(
    const f16* __restrict__ Hl, const f16* __restrict__ Zs,
    const float* __restrict__ sC, const f16* __restrict__ expBT,
    const f16* __restrict__ Carry, f16* __restrict__ Y)
{
  const int r = threadIdx.x >> 6, lane = threadIdx.x & 63;
  const int m = blockIdx.y * 4 + r;
  const int d0 = blockIdx.x * 512 + lane * 8;
  const int b = m >> 11, t = m & (SLEN - 1);
  const int ch = t / CHUNK, tl = t & (CHUNK - 1);

  float coef = 0.f;
  if (ch > 0) {
    coef = 1.f;
    for (int j = 0; j <= tl; ++j) coef *= DECAYF;
  }

  const float4 sc0 = *(const float4*)&sC[m * 16 + 0];
  const float4 sc1 = *(const float4*)&sC[m * 16 + 4];
  const float4 sc2 = *(const float4*)&sC[m * 16 + 8];
  const float4 sc3 = *(const float4*)&sC[m * 16 + 12];
  const float scv[16] = {sc0.x, sc0.y, sc0.z, sc0.w, sc1.x, sc1.y, sc1.z, sc1.w,
                         sc2.x, sc2.y, sc2.z, sc2.w, sc3.x, sc3.y, sc3.z, sc3.w};

  const size_t ro = (size_t)m * DI + d0;
  f16x8 hvv = *(const f16x8*)&Hl[ro];
  f16x8 zvv = *(const f16x8*)&Zs[ro];
  float hv[8], zv[8], ca[8];
  #pragma unroll
  for (int i = 0; i < 8; ++i) {
    hv[i] = (float)hvv[i];
    zv[i] = silu_f((float)zvv[i]);
    ca[i] = 0.f;
  }
  if (ch > 0) {
    const size_t co = ((size_t)(b * NCH + ch - 1)) * DI + d0;
    f16x8 cv = *(const f16x8*)&Carry[co];
    #pragma unroll
    for (int i = 0; i < 8; ++i) ca[i] = (float)cv[i];
  }

  float cp[8] = {0.f, 0.f, 0.f, 0.f, 0.f, 0.f, 0.f, 0.f};
  #pragma unroll
  for (int n = 0; n < 16; ++n) {
    f16x8 ev = *(const f16x8*)&expBT[(size_t)n * DI + d0];
    #pragma unroll
    for (int i = 0; i < 8; ++i) cp[i] += scv[n] * (float)ev[i];
  }

  f16x8 o;
  #pragma unroll
  for (int i = 0; i < 8; ++i) {
    float y = (hv[i] + coef * ca[i]) * cp[i] * zv[i];
    o[i] = (f16)y;
  }
  *(f16x8*)&Y[ro] = o;
}

// ---------------- residual + LayerNorm (row = 1024), G is f16 ----------------
__global__ __launch_bounds__(256) void ln_res(const f16* __restrict__ G, const float* __restrict__ x,
                                              const float* __restrict__ lng, const float* __restrict__ lnb,
                                              float* __restrict__ out) {
  const int m = blockIdx.x;
  const int tid = threadIdx.x;
  f16x4 gv4 = ((const f16x4*)(G + (size_t)m * DM))[tid];
  float4 xv = ((const float4*)(x + (size_t)m * DM))[tid];
  float4 rv = {(float)gv4.x + xv.x, (float)gv4.y + xv.y, (float)gv4.z + xv.z, (float)gv4.w + xv.w};
  float s = rv.x + rv.y + rv.z + rv.w;
  float s2 = rv.x * rv.x + rv.y * rv.y + rv.z * rv.z + rv.w * rv.w;
  #pragma unroll
  for (int off = 32; off > 0; off >>= 1) {
    s += __shfl_xor(s, off);
    s2 += __shfl_xor(s2, off);
  }
  __shared__ float ps[8];
  const int w = tid >> 6;
  if ((tid & 63) == 0) { ps[w] = s; ps[w + 4] = s2; }
  __syncthreads();
  float S = ps[0] + ps[1] + ps[2] + ps[3];
  float S2 = ps[4] + ps[5] + ps[6] + ps[7];
  float mu = S * (1.f / DM);
  float var = S2 * (1.f / DM) - mu * mu;
  float rs = rsqrtf(var + 1e-5f);
  float4 gg = ((const float4*)lng)[tid];
  float4 bb = ((const float4*)lnb)[tid];
  float4 ov = {(rv.x - mu) * rs * gg.x + bb.x, (rv.y - mu) * rs * gg.y + bb.y,
               (rv.z - mu) * rs * gg.z + bb.z, (rv.w - mu) * rs * gg.w + bb.w};
  ((float4*)(out + (size_t)m * DM))[tid] = ov;
}

extern "C" void kernel_launch(void* const* d_in, const int* in_sizes, int n_in,
                              void* d_out, int out_size, void* d_ws, size_t ws_size,
                              hipStream_t stream) {
  const float* x      = (const float*)d_in[0];
  const float* W_in   = (const float*)d_in[1];
  const float* conv_w = (const float*)d_in[2];
  const float* conv_b = (const float*)d_in[3];
  const float* W_x    = (const float*)d_in[4];
  const float* B_log  = (const float*)d_in[5];
  const float* W_out  = (const float*)d_in[6];
  const float* ln_g   = (const float*)d_in[7];
  const float* ln_b   = (const float*)d_in[8];
  float* out = (float*)d_out;

  char* ws = (char*)d_ws;
  f16*   Xi  = (f16*)(ws + 0);
  f16*   Yp  = (f16*)(ws + 0);
  f16*   Zs  = (f16*)(ws + 32 * MB);
  f16*   Xc  = (f16*)(ws + 64 * MB);
  f16*   Hl  = (f16*)(ws + 96 * MB);
  f16*   A1  = (f16*)(ws + 128 * MB);
  f16*   B1  = (f16*)(ws + 144 * MB);
  f16*   W2  = (f16*)(ws + 152 * MB);
  f16*   G   = (f16*)(ws + 156 * MB);
  float* L     = (float*)(ws + 172 * MB);
  f16*   Carry = (f16*)(ws + 174 * MB);
  float* sC    = (float*)(ws + 175 * MB);
  f16*   expBT = (f16*)(ws + 176 * MB);
  f16*   WxC   = (f16*)(ws + 177 * MB);

  cvt_all<<<(NX4 + NWI4 + NWO4 + NWX4 + NE4) / 256, 256, 0, stream>>>(
      x, W_in, W_out, W_x, B_log, A1, B1, W2, WxC, expBT);

  // GEMM1 (4-slot BK=32, merged 32-MFMA phases): [8192 x 4096] = A1 * B1^T
  gemm1_8ph<<<dim3(2 * DI / 256, MROWS / 256), 512, 0, stream>>>(A1, B1, Xi, Zs);

  conv_scan<<<dim3(NCH, BSZ), 256, 0, stream>>>(Xi, conv_w, conv_b, Xc, Hl, L);
  sc_carry<<<2048 + 32, 256, 0, stream>>>(Xc, WxC, L, sC, Carry);
  ew_y<<<dim3(DI / 512, MROWS / 4), 256, 0, stream>>>(Hl, Zs, sC, expBT, Carry, Yp);

  // GEMM2 (4-slot BK=32 pipeline, 256x128 tile): [8192 x 1024] = Yp * W2^T -> G f16
  gemm2_pipe<<<dim3(DM / 128, MROWS / 256), 512, 0, stream>>>(Yp, W2, G);

  ln_res<<<MROWS, 256, 0, stream>>>(G, x, ln_g, ln_b, out);
}

// Round 18
// 245.592 us; speedup vs baseline: 1.0150x; 1.0150x over previous
//
#include <hip/hip_runtime.h>
#include <hip/hip_bf16.h>
#include <stdint.h>

#define DM   1024
#define DI   2048
#define NST  16
#define BSZ  4
#define SLEN 2048
#define MROWS (BSZ*SLEN)   // 8192
#define CHUNK 32
#define NCH  (SLEN/CHUNK)  // 64
#define DECAYF 0.95f
#define MB (size_t)1048576

typedef _Float16 f16;
typedef __attribute__((ext_vector_type(2))) _Float16 f16x2;
typedef __attribute__((ext_vector_type(4))) _Float16 f16x4;
typedef __attribute__((ext_vector_type(8))) _Float16 f16x8;
typedef __attribute__((ext_vector_type(4))) float f32x4;

__device__ __forceinline__ float silu_f(float v) { return v / (1.f + __expf(-v)); }

__device__ __forceinline__ void gload16(const f16* lds, const f16* g) {
  __builtin_amdgcn_global_load_lds((const __attribute__((address_space(1))) void*)g,
                                   (__attribute__((address_space(3))) void*)lds, 16, 0, 0);
}

// ---- fused preprocessing: x->A1, W_in->B1, W_out->W2, W_x[16:32)->WxC f16, B_log->expBT f16 ----
#define NX4  (MROWS * DM / 4)          // 2,097,152
#define NWI4 (2 * DI * DM / 4)         // 1,048,576
#define NWO4 (DM * DI / 4)             // 524,288
#define NWX4 (NST * DI / 4)            // 8,192
#define NE4  (NST * DI / 4)            // 8,192
__global__ __launch_bounds__(256) void cvt_all(
    const float* __restrict__ x, const float* __restrict__ wi, const float* __restrict__ wo,
    const float* __restrict__ Wx, const float* __restrict__ B_log,
    f16* __restrict__ A1, f16* __restrict__ B1, f16* __restrict__ W2,
    f16* __restrict__ WxC, f16* __restrict__ expBT)
{
  int i = blockIdx.x * 256 + threadIdx.x;
  if (i < NX4 + NWI4 + NWO4 + NWX4) {
    const float* src; f16* dst; int j;
    if (i < NX4)                     { src = x;  dst = A1; j = i; }
    else if (i < NX4 + NWI4)         { src = wi; dst = B1; j = i - NX4; }
    else if (i < NX4 + NWI4 + NWO4)  { src = wo; dst = W2; j = i - NX4 - NWI4; }
    else                             { src = Wx + (size_t)NST * DI; dst = WxC; j = i - NX4 - NWI4 - NWO4; }
    float4 v = ((const float4*)src)[j];
    f16x4 o = {(f16)v.x, (f16)v.y, (f16)v.z, (f16)v.w};
    ((f16x4*)dst)[j] = o;
  } else {
    int j = i - NX4 - NWI4 - NWO4 - NWX4;  // [0, NE4)
    int base = j * 4;                      // element index n*DI+d
    int n = base >> 11, d = base & (DI - 1);
    f16x4 o = {(f16)__expf(B_log[(d + 0) * NST + n]), (f16)__expf(B_log[(d + 1) * NST + n]),
               (f16)__expf(B_log[(d + 2) * NST + n]), (f16)__expf(B_log[(d + 3) * NST + n])};
    ((f16x4*)expBT)[j] = o;
  }
}

// ======= GEMM1: 256x256 tile, BK=32, 4-slot LDS rotation, depth-3 counted-vmcnt =======
#define G1K 1024

__device__ __forceinline__ void stage_t(const f16* __restrict__ mat, int matBase,
                                        int kt, f16* ldsDst, int tid) {
  #pragma unroll
  for (int q = 0; q < 2; ++q) {
    int c = q * 512 + tid;
    int row = c >> 2, p = c & 3;
    int su = p ^ ((row >> 1) & 3);   // pre-swizzled source -> swizzled LDS layout
    gload16(ldsDst + c * 8, mat + (size_t)(matBase + row) * G1K + kt * 32 + su * 8);
  }
}

#define WAITV(n) asm volatile("s_waitcnt vmcnt(" #n ")" ::: "memory")

__global__ __launch_bounds__(512, 2) void gemm1_8ph(
    const f16* __restrict__ A, const f16* __restrict__ Bt,
    f16* __restrict__ Xi, f16* __restrict__ Zs)
{
  __shared__ __align__(16) f16 lds[65536];  // 128KB = 4 slots x 32KB (A@S, B@S+8192)
  const int tid  = threadIdx.x;
  const int lane = tid & 63;
  const int w    = tid >> 6;
  const int wr   = w >> 2, wc = w & 3;
  const int lr   = lane & 15;
  const int lq   = lane >> 4;

  const int nwg = gridDim.x * gridDim.y;
  int wgid = blockIdx.y * gridDim.x + blockIdx.x;
  wgid = (wgid & 7) * (nwg >> 3) + (wgid >> 3);
  const int bx = wgid % gridDim.x;
  const int by = wgid / gridDim.x;
  const int mBase = by * 256;
  const int nBase = bx * 256;

  f32x4 acc[8][4];
  #pragma unroll
  for (int mf = 0; mf < 8; ++mf)
    #pragma unroll
    for (int nf = 0; nf < 4; ++nf)
      acc[mf][nf] = (f32x4){0.f, 0.f, 0.f, 0.f};

  auto rdA = [&](int S, int mf) -> f16x8 {
    int ra = wr * 128 + mf * 16 + lr;
    return *(const f16x8*)&lds[S + ra * 32 + (lq ^ ((ra >> 1) & 3)) * 8];
  };
  auto rdB = [&](int S, int nf) -> f16x8 {
    int rb = wc * 64 + nf * 16 + lr;
    return *(const f16x8*)&lds[S + 8192 + rb * 32 + (lq ^ ((rb >> 1) & 3)) * 8];
  };

  f16x8 bfr[4], afr[8];

#define PH(S, ISSUE, TAIL) do {                                                 \
    _Pragma("unroll")                                                           \
    for (int nf = 0; nf < 4; ++nf) bfr[nf] = rdB((S), nf);                      \
    _Pragma("unroll")                                                           \
    for (int mm = 0; mm < 8; ++mm) afr[mm] = rdA((S), mm);                      \
    ISSUE;                                                                      \
    __builtin_amdgcn_s_barrier();                                               \
    asm volatile("s_waitcnt lgkmcnt(0)" ::: "memory");                          \
    __builtin_amdgcn_sched_barrier(0);                                          \
    __builtin_amdgcn_s_setprio(1);                                              \
    _Pragma("unroll")                                                           \
    for (int mm = 0; mm < 8; ++mm)                                              \
      _Pragma("unroll")                                                         \
      for (int nf = 0; nf < 4; ++nf)                                            \
        acc[mm][nf] = __builtin_amdgcn_mfma_f32_16x16x32_f16(                   \
            afr[mm], bfr[nf], acc[mm][nf], 0, 0, 0);                            \
    __builtin_amdgcn_s_setprio(0);                                              \
    __builtin_amdgcn_sched_barrier(0);                                          \
    TAIL;                                                                       \
    __builtin_amdgcn_s_barrier();                                               \
  } while (0)

  stage_t(A,  mBase, 0, &lds[0],             tid);
  stage_t(Bt, nBase, 0, &lds[8192],          tid);
  stage_t(A,  mBase, 1, &lds[16384],         tid);
  stage_t(Bt, nBase, 1, &lds[16384 + 8192],  tid);
  stage_t(A,  mBase, 2, &lds[32768],         tid);
  stage_t(Bt, nBase, 2, &lds[32768 + 8192],  tid);
  WAITV(8);
  __builtin_amdgcn_s_barrier();

  #pragma unroll
  for (int T = 0; T < 32; ++T) {
    const int S = (T & 3) * 16384;
    const int F = ((T + 3) & 3) * 16384;
    PH(S,
       { if (T + 3 < 32) { stage_t(A, mBase, T + 3, &lds[F], tid);
                           stage_t(Bt, nBase, T + 3, &lds[F + 8192], tid); } },
       { if (T < 29) { WAITV(8); } else if (T == 29) { WAITV(4); } else if (T == 30) { WAITV(0); } });
  }
#undef PH

  __syncthreads();
  const int rq = lq * 4;
  #pragma unroll
  for (int mf = 0; mf < 8; ++mf)
    #pragma unroll
    for (int nf = 0; nf < 4; ++nf)
      #pragma unroll
      for (int r = 0; r < 4; ++r)
        lds[(wr * 128 + mf * 16 + rq + r) * 256 + wc * 64 + nf * 16 + lr] = (f16)acc[mf][nf][r];
  __syncthreads();
  #pragma unroll
  for (int it = 0; it < 16; ++it) {
    int cidx = it * 512 + tid;
    int row = cidx >> 5;
    int col8 = (cidx & 31) * 8;
    int grow = mBase + row;
    int gcol = nBase + col8;
    f16x8 v = *(const f16x8*)&lds[row * 256 + col8];
    if (gcol < DI) *(f16x8*)&Xi[(size_t)grow * DI + gcol] = v;
    else           *(f16x8*)&Zs[(size_t)grow * DI + (gcol - DI)] = v;
  }
}

// ======= GEMM2: 256x128 tile, BK=32, 4-slot rotation, depth-3 counted-vmcnt =======
#define G2K 2048
#define SLOT2 12288   // f16 units per slot: A 256x32 (8192) + B 128x32 (4096)

__device__ __forceinline__ void stage2_A(const f16* __restrict__ mat, int mBase,
                                         int kt, f16* ldsDst, int tid) {
  #pragma unroll
  for (int q = 0; q < 2; ++q) {
    int c = q * 512 + tid;
    int row = c >> 2, p = c & 3;
    int su = p ^ ((row >> 1) & 3);
    gload16(ldsDst + c * 8, mat + (size_t)(mBase + row) * G2K + kt * 32 + su * 8);
  }
}
__device__ __forceinline__ void stage2_B(const f16* __restrict__ mat, int nBase,
                                         int kt, f16* ldsDst, int tid) {
  int c = tid;
  int row = c >> 2, p = c & 3;
  int su = p ^ ((row >> 1) & 3);
  gload16(ldsDst + c * 8, mat + (size_t)(nBase + row) * G2K + kt * 32 + su * 8);
}

__global__ __launch_bounds__(512, 2) void gemm2_pipe(
    const f16* __restrict__ A, const f16* __restrict__ Bt, f16* __restrict__ G)
{
  __shared__ __align__(16) f16 lds[49152];  // 96KB = 4 slots x 24KB
  const int tid  = threadIdx.x;
  const int lane = tid & 63;
  const int w    = tid >> 6;
  const int wr   = w >> 2, wc = w & 3;
  const int lr   = lane & 15;
  const int lq   = lane >> 4;

  const int nwg = gridDim.x * gridDim.y;   // 256, %8==0
  int wgid = blockIdx.y * gridDim.x + blockIdx.x;
  wgid = (wgid & 7) * (nwg >> 3) + (wgid >> 3);
  const int bx = wgid % gridDim.x;
  const int by = wgid / gridDim.x;
  const int mBase = by * 256;
  const int nBase = bx * 128;

  f32x4 acc[8][2];
  #pragma unroll
  for (int mf = 0; mf < 8; ++mf)
    #pragma unroll
    for (int nf = 0; nf < 2; ++nf)
      acc[mf][nf] = (f32x4){0.f, 0.f, 0.f, 0.f};

  auto rdA = [&](int S, int mf) -> f16x8 {
    int ra = wr * 128 + mf * 16 + lr;
    return *(const f16x8*)&lds[S + ra * 32 + (lq ^ ((ra >> 1) & 3)) * 8];
  };
  auto rdB = [&](int S, int nf) -> f16x8 {
    int rb = wc * 32 + nf * 16 + lr;
    return *(const f16x8*)&lds[S + 8192 + rb * 32 + (lq ^ ((rb >> 1) & 3)) * 8];
  };

  f16x8 bfr[2], afr[8];

#define PH2(S, ISSUE, TAIL) do {                                                \
    _Pragma("unroll")                                                           \
    for (int nf = 0; nf < 2; ++nf) bfr[nf] = rdB((S), nf);                      \
    _Pragma("unroll")                                                           \
    for (int mm = 0; mm < 8; ++mm) afr[mm] = rdA((S), mm);                      \
    ISSUE;                                                                      \
    __builtin_amdgcn_s_barrier();                                               \
    asm volatile("s_waitcnt lgkmcnt(0)" ::: "memory");                          \
    __builtin_amdgcn_sched_barrier(0);                                          \
    __builtin_amdgcn_s_setprio(1);                                              \
    _Pragma("unroll")                                                           \
    for (int mm = 0; mm < 8; ++mm)                                              \
      _Pragma("unroll")                                                         \
      for (int nf = 0; nf < 2; ++nf)                                            \
        acc[mm][nf] = __builtin_amdgcn_mfma_f32_16x16x32_f16(                   \
            afr[mm], bfr[nf], acc[mm][nf], 0, 0, 0);                            \
    __builtin_amdgcn_s_setprio(0);                                              \
    __builtin_amdgcn_sched_barrier(0);                                          \
    TAIL;                                                                       \
    __builtin_amdgcn_s_barrier();                                               \
  } while (0)

  stage2_A(A,  mBase, 0, &lds[0],                 tid);
  stage2_B(Bt, nBase, 0, &lds[8192],              tid);
  stage2_A(A,  mBase, 1, &lds[SLOT2],             tid);
  stage2_B(Bt, nBase, 1, &lds[SLOT2 + 8192],      tid);
  stage2_A(A,  mBase, 2, &lds[2 * SLOT2],         tid);
  stage2_B(Bt, nBase, 2, &lds[2 * SLOT2 + 8192],  tid);
  WAITV(6);
  __builtin_amdgcn_s_barrier();

  #pragma unroll
  for (int T = 0; T < 64; ++T) {
    const int S = (T & 3) * SLOT2;
    const int F = ((T + 3) & 3) * SLOT2;
    PH2(S,
        { if (T + 3 < 64) { stage2_A(A, mBase, T + 3, &lds[F], tid);
                            stage2_B(Bt, nBase, T + 3, &lds[F + 8192], tid); } },
        { if (T < 61) { WAITV(6); } else if (T == 61) { WAITV(3); } else if (T == 62) { WAITV(0); } });
  }
#undef PH2

  __syncthreads();
  const int rq = lq * 4;
  #pragma unroll
  for (int mf = 0; mf < 8; ++mf)
    #pragma unroll
    for (int nf = 0; nf < 2; ++nf)
      #pragma unroll
      for (int r = 0; r < 4; ++r)
        lds[(wr * 128 + mf * 16 + rq + r) * 128 + wc * 32 + nf * 16 + lr] = (f16)acc[mf][nf][r];
  __syncthreads();
  #pragma unroll
  for (int it = 0; it < 8; ++it) {
    int cidx = it * 512 + tid;
    int row = cidx >> 4;
    int col8 = (cidx & 15) * 8;
    f16x8 v = *(const f16x8*)&lds[row * 128 + col8];
    *(f16x8*)&G[(size_t)(mBase + row) * DM + nBase + col8] = v;
  }
}

// ---- fused conv + SiLU + local scan + s_C projection (no Xc buffer) ----
// grid: (NCH, BSZ), block 256, 8 d/thread (f16x8). Per t: conv+scan, then 16-wide
// s_C partial from in-register xc, wave-reduced, block-reduced via 8KB LDS.
__global__ __launch_bounds__(256) void conv_sc(
    const f16* __restrict__ Xi, const float* __restrict__ convW, const float* __restrict__ convB,
    const f16* __restrict__ WxC,
    f16* __restrict__ Hl, float* __restrict__ L, float* __restrict__ sC)
{
  __shared__ float red[CHUNK][4][16];  // 8KB wave-partials
  const int tid = threadIdx.x;
  const int d0 = tid * 8;
  const int wave = tid >> 6, lane = tid & 63;
  const int ch = blockIdx.x;
  const int b  = blockIdx.y;
  const int t0 = ch * CHUNK;

  float w0[8], w1[8], w2[8], w3[8], cb[8];
  #pragma unroll
  for (int i = 0; i < 8; ++i) {
    float4 wv = ((const float4*)convW)[d0 + i];
    w0[i] = wv.x; w1[i] = wv.y; w2[i] = wv.z; w3[i] = wv.w;
    cb[i] = convB[d0 + i];
  }
  f16x8 wx[16];
  #pragma unroll
  for (int n = 0; n < 16; ++n) wx[n] = *(const f16x8*)&WxC[(size_t)n * DI + d0];

  float xm3[8], xm2[8], xm1[8];
  auto loadrow = [&](int t, float* dst) {
    if (t < 0) {
      #pragma unroll
      for (int i = 0; i < 8; ++i) dst[i] = 0.f;
      return;
    }
    f16x8 v = *(const f16x8*)&Xi[((size_t)(b * SLEN + t)) * DI + d0];
    #pragma unroll
    for (int i = 0; i < 8; ++i) dst[i] = (float)v[i];
  };
  loadrow(t0 - 3, xm3); loadrow(t0 - 2, xm2); loadrow(t0 - 1, xm1);

  float h[8] = {0.f, 0.f, 0.f, 0.f, 0.f, 0.f, 0.f, 0.f};
  for (int t = 0; t < CHUNK; ++t) {
    const size_t ro = ((size_t)(b * SLEN + t0 + t)) * DI + d0;
    f16x8 xv = *(const f16x8*)&Xi[ro];
    f16x8 hho;
    float xc[8];
    #pragma unroll
    for (int i = 0; i < 8; ++i) {
      float xt = (float)xv[i];
      float c = cb[i] + w0[i]*xm3[i] + w1[i]*xm2[i] + w2[i]*xm1[i] + w3[i]*xt;
      xc[i] = silu_f(c);
      h[i] = DECAYF * h[i] + xc[i];
      hho[i] = (f16)h[i];
      xm3[i] = xm2[i]; xm2[i] = xm1[i]; xm1[i] = xt;
    }
    *(f16x8*)&Hl[ro] = hho;
    // s_C partials: s[n] = sum_i xc[i] * WxC[n][d0+i], reduced across the wave
    float s[16];
    #pragma unroll
    for (int n = 0; n < 16; ++n) {
      float v = 0.f;
      #pragma unroll
      for (int i = 0; i < 8; ++i) v += xc[i] * (float)wx[n][i];
      s[n] = v;
    }
    #pragma unroll
    for (int n = 0; n < 16; ++n) {
      #pragma unroll
      for (int off = 32; off > 0; off >>= 1) s[n] += __shfl_xor(s[n], off);
    }
    if (lane == 0) {
      #pragma unroll
      for (int n = 0; n < 16; ++n) red[t][wave][n] = s[n];
    }
  }
  const size_t lo = ((size_t)(b * NCH + ch)) * DI + d0;
  float4 l0 = {h[0], h[1], h[2], h[3]};
  float4 l1 = {h[4], h[5], h[6], h[7]};
  *(float4*)&L[lo] = l0;
  *(float4*)&L[lo + 4] = l1;

  __syncthreads();
  #pragma unroll
  for (int k = 0; k < 2; ++k) {
    int idx = k * 256 + tid;          // 512 = CHUNK*16 values
    int t = idx >> 4, n = idx & 15;
    float v = red[t][0][n] + red[t][1][n] + red[t][2][n] + red[t][3][n];
    sC[((size_t)(b * SLEN + t0 + t)) * 16 + n] = v;
  }
}

// ---------------- sequential chunk-carry (8-wide batched loads), f16 output ----------------
__global__ void carry_scan(const float* __restrict__ L, f16* __restrict__ Carry) {
  int i = blockIdx.x * blockDim.x + threadIdx.x;  // 8192
  int b = i >> 11, d = i & (DI - 1);
  float dp = 1.f;
  #pragma unroll
  for (int k = 0; k < CHUNK; ++k) dp *= DECAYF;
  float c = 0.f;
  for (int ch0 = 0; ch0 < NCH; ch0 += 8) {
    float lv[8];
    #pragma unroll
    for (int k = 0; k < 8; ++k)
      lv[k] = L[((size_t)(b * NCH + ch0 + k)) * DI + d];
    #pragma unroll
    for (int k = 0; k < 8; ++k) {
      c = dp * c + lv[k];
      Carry[((size_t)(b * NCH + ch0 + k)) * DI + d] = (f16)c;
    }
  }
}

// ---------------- Y = (Hl + coef*Carry) * (sC·expBT) * silu(Z) ; f16 out ----------------
__global__ __launch_bounds__(256) void ew_y(
    const f16* __restrict__ Hl, const f16* __restrict__ Zs,
    const float* __restrict__ sC, const f16* __restrict__ expBT,
    const f16* __restrict__ Carry, f16* __restrict__ Y)
{
  const int r = threadIdx.x >> 6, lane = threadIdx.x & 63;
  const int m = blockIdx.y * 4 + r;
  const int d0 = blockIdx.x * 512 + lane * 8;
  const int b = m >> 11, t = m & (SLEN - 1);
  const int ch = t / CHUNK, tl = t & (CHUNK - 1);

  float coef = 0.f;
  if (ch > 0) {
    coef = 1.f;
    for (int j = 0; j <= tl; ++j) coef *= DECAYF;
  }

  const float4 sc0 = *(const float4*)&sC[m * 16 + 0];
  const float4 sc1 = *(const float4*)&sC[m * 16 + 4];
  const float4 sc2 = *(const float4*)&sC[m * 16 + 8];
  const float4 sc3 = *(const float4*)&sC[m * 16 + 12];
  const float scv[16] = {sc0.x, sc0.y, sc0.z, sc0.w, sc1.x, sc1.y, sc1.z, sc1.w,
                         sc2.x, sc2.y, sc2.z, sc2.w, sc3.x, sc3.y, sc3.z, sc3.w};

  const size_t ro = (size_t)m * DI + d0;
  f16x8 hvv = *(const f16x8*)&Hl[ro];
  f16x8 zvv = *(const f16x8*)&Zs[ro];
  float hv[8], zv[8], ca[8];
  #pragma unroll
  for (int i = 0; i < 8; ++i) {
    hv[i] = (float)hvv[i];
    zv[i] = silu_f((float)zvv[i]);
    ca[i] = 0.f;
  }
  if (ch > 0) {
    const size_t co = ((size_t)(b * NCH + ch - 1)) * DI + d0;
    f16x8 cv = *(const f16x8*)&Carry[co];
    #pragma unroll
    for (int i = 0; i < 8; ++i) ca[i] = (float)cv[i];
  }

  float cp[8] = {0.f, 0.f, 0.f, 0.f, 0.f, 0.f, 0.f, 0.f};
  #pragma unroll
  for (int n = 0; n < 16; ++n) {
    f16x8 ev = *(const f16x8*)&expBT[(size_t)n * DI + d0];
    #pragma unroll
    for (int i = 0; i < 8; ++i) cp[i] += scv[n] * (float)ev[i];
  }

  f16x8 o;
  #pragma unroll
  for (int i = 0; i < 8; ++i) {
    float y = (hv[i] + coef * ca[i]) * cp[i] * zv[i];
    o[i] = (f16)y;
  }
  *(f16x8*)&Y[ro] = o;
}

// ---------------- residual + LayerNorm (row = 1024), G is f16 ----------------
__global__ __launch_bounds__(256) void ln_res(const f16* __restrict__ G, const float* __restrict__ x,
                                              const float* __restrict__ lng, const float* __restrict__ lnb,
                                              float* __restrict__ out) {
  const int m = blockIdx.x;
  const int tid = threadIdx.x;
  f16x4 gv4 = ((const f16x4*)(G + (size_t)m * DM))[tid];
  float4 xv = ((const float4*)(x + (size_t)m * DM))[tid];
  float4 rv = {(float)gv4.x + xv.x, (float)gv4.y + xv.y, (float)gv4.z + xv.z, (float)gv4.w + xv.w};
  float s = rv.x + rv.y + rv.z + rv.w;
  float s2 = rv.x * rv.x + rv.y * rv.y + rv.z * rv.z + rv.w * rv.w;
  #pragma unroll
  for (int off = 32; off > 0; off >>= 1) {
    s += __shfl_xor(s, off);
    s2 += __shfl_xor(s2, off);
  }
  __shared__ float ps[8];
  const int w = tid >> 6;
  if ((tid & 63) == 0) { ps[w] = s; ps[w + 4] = s2; }
  __syncthreads();
  float S = ps[0] + ps[1] + ps[2] + ps[3];
  float S2 = ps[4] + ps[5] + ps[6] + ps[7];
  float mu = S * (1.f / DM);
  float var = S2 * (1.f / DM) - mu * mu;
  float rs = rsqrtf(var + 1e-5f);
  float4 gg = ((const float4*)lng)[tid];
  float4 bb = ((const float4*)lnb)[tid];
  float4 ov = {(rv.x - mu) * rs * gg.x + bb.x, (rv.y - mu) * rs * gg.y + bb.y,
               (rv.z - mu) * rs * gg.z + bb.z, (rv.w - mu) * rs * gg.w + bb.w};
  ((float4*)(out + (size_t)m * DM))[tid] = ov;
}

extern "C" void kernel_launch(void* const* d_in, const int* in_sizes, int n_in,
                              void* d_out, int out_size, void* d_ws, size_t ws_size,
                              hipStream_t stream) {
  const float* x      = (const float*)d_in[0];
  const float* W_in   = (const float*)d_in[1];
  const float* conv_w = (const float*)d_in[2];
  const float* conv_b = (const float*)d_in[3];
  const float* W_x    = (const float*)d_in[4];
  const float* B_log  = (const float*)d_in[5];
  const float* W_out  = (const float*)d_in[6];
  const float* ln_g   = (const float*)d_in[7];
  const float* ln_b   = (const float*)d_in[8];
  float* out = (float*)d_out;

  char* ws = (char*)d_ws;
  f16*   Xi  = (f16*)(ws + 0);
  f16*   Yp  = (f16*)(ws + 0);
  f16*   Zs  = (f16*)(ws + 32 * MB);
  f16*   Hl  = (f16*)(ws + 96 * MB);
  f16*   A1  = (f16*)(ws + 128 * MB);
  f16*   B1  = (f16*)(ws + 144 * MB);
  f16*   W2  = (f16*)(ws + 152 * MB);
  f16*   G   = (f16*)(ws + 156 * MB);
  float* L     = (float*)(ws + 172 * MB);
  f16*   Carry = (f16*)(ws + 174 * MB);
  float* sC    = (float*)(ws + 175 * MB);
  f16*   expBT = (f16*)(ws + 176 * MB);
  f16*   WxC   = (f16*)(ws + 177 * MB);

  cvt_all<<<(NX4 + NWI4 + NWO4 + NWX4 + NE4) / 256, 256, 0, stream>>>(
      x, W_in, W_out, W_x, B_log, A1, B1, W2, WxC, expBT);

  // GEMM1 (4-slot BK=32, merged 32-MFMA phases): [8192 x 4096] = A1 * B1^T
  gemm1_8ph<<<dim3(2 * DI / 256, MROWS / 256), 512, 0, stream>>>(A1, B1, Xi, Zs);

  // fused conv+scan+s_C (no Xc buffer)
  conv_sc<<<dim3(NCH, BSZ), 256, 0, stream>>>(Xi, conv_w, conv_b, WxC, Hl, L, sC);
  carry_scan<<<(BSZ * DI) / 256, 256, 0, stream>>>(L, Carry);
  ew_y<<<dim3(DI / 512, MROWS / 4), 256, 0, stream>>>(Hl, Zs, sC, expBT, Carry, Yp);

  // GEMM2 (4-slot BK=32 pipeline, 256x128 tile): [8192 x 1024] = Yp * W2^T -> G f16
  gemm2_pipe<<<dim3(DM / 128, MROWS / 256), 512, 0, stream>>>(Yp, W2, G);

  ln_res<<<MROWS, 256, 0, stream>>>(G, x, ln_g, ln_b, out);
}